// Round 3
// baseline (1435.480 us; speedup 1.0000x reference)
//
#include <hip/hip_runtime.h>
#include <hip/hip_bf16.h>

typedef float v4f __attribute__((ext_vector_type(4)));

#define NQ 2048
#define NB 512        // rows b
#define NX 256        // kernel centers per row
#define NR 1024       // grid resolution
#define KDE_EPS 1e-6f
#define PS4 131072    // float4 per bank slot (2^17)
// C = log(256) + log(0.1) + log(sqrt(2*pi))
#define LOGC 4.1615308846901885f
#define NORM 0.015583685919813959f       // exp(-LOGC)
#define SCALE 8.4932180028801903f        // 10 * sqrt(0.5*log2(e)): exp(-0.5*(10z)^2) = exp2(-(z*SCALE)^2)

#define NEVAL 2048                        // eval blocks (512 rows x 4 chunks)
#define EVAL_SPAN 65536                   // eval blocks interleaved 1:31 in [0, EVAL_SPAN)
#define NCOPY 64512                       // 126 slots * 512 blocks/slot
#define GRID_TOTAL (NCOPY + NEVAL)        // 66560

// One kernel, heterogeneous grid:
//  - blocks with (bx < EVAL_SPAN && bx%32==0): compute row stats + evaluate
//    current/transformed KDE on the grids (VALU-bound, hidden under copy)
//  - all other blocks: stream bank slots 2..127 to out (out[slot_idx] <- bank[0])
__global__ __launch_bounds__(256) void kde_fused(
    const float* __restrict__ inputs,    // (256, 512)
    const v4f*   __restrict__ bank4,     // (128, 512, 1024) as vec4
    const float* __restrict__ noise,     // (512, 2048)
    const int*   __restrict__ comp_idx,  // (512, 2048)
    const int*   __restrict__ sel,       // (512,)
    const int*   __restrict__ slotp,     // scalar
    float*       __restrict__ out)       // (128, 512, 1024)
{
    const unsigned bx = blockIdx.x;
    const int tid = threadIdx.x;

    const bool is_eval = (bx < EVAL_SPAN) && ((bx & 31u) == 0u);
    if (!is_eval) {
        // ---------------- copy path ----------------
        const int slot_idx = *slotp;
        const size_t ci = (bx < EVAL_SPAN) ? (size_t)(bx - (bx >> 5) - 1u)
                                           : (size_t)(bx - NEVAL);
        v4f* __restrict__ out4 = (v4f*)out;
        const size_t i = (size_t)2 * PS4 + ci * 256 + tid;   // slots 2..127
        const int slot = (int)(i >> 17);
        const size_t src = (slot == slot_idx) ? (i & (size_t)(PS4 - 1)) : i;
        v4f v = __builtin_nontemporal_load(&bank4[src]);
        __builtin_nontemporal_store(v, &out4[i]);
        // generality patch: if slot_idx < 2, out[slot_idx] <- bank[0]
        if (slot_idx < 2 && ci < 512) {
            const size_t pos = ci * 256 + tid;
            v4f v2 = __builtin_nontemporal_load(&bank4[pos]);
            __builtin_nontemporal_store(v2, &out4[(size_t)slot_idx * PS4 + pos]);
        }
        return;
    }

    // ---------------- eval path ----------------
    const unsigned e = bx >> 5;          // 0..2047
    const int b     = (int)(e >> 2);     // row
    const int chunk = (int)(e & 3u);     // 256-wide chunk of the 1024 grid
    const int selb  = sel[b];

    __shared__ float xsS[NX];            // x column pre-scaled by SCALE
    __shared__ float red[4][4];
    __shared__ float sst[4];

    xsS[tid] = inputs[tid * NB + b] * SCALE;

    // per-row min/max of samples and of y = f_sel(samples); samples never stored
    float mns =  INFINITY, mxs = -INFINITY;
    float mny =  INFINITY, mxy = -INFINITY;
    for (int q = tid; q < NQ; q += 256) {
        const int   idx = comp_idx[b * NQ + q];
        const float s   = inputs[idx * NB + b] + 0.1f * noise[b * NQ + q];
        mns = fminf(mns, s);  mxs = fmaxf(mxs, s);
        const float ssafe = (fabsf(s) < KDE_EPS) ? KDE_EPS : s;
        float y;
        switch (selb) {
            case 0:  y = 2.0f * s; break;
            case 1:  y = s - 3.0f; break;
            case 2:  y = 1.0f / ssafe; break;
            case 3:  y = 0.8f * s + 5.0f; break;
            case 4:  y = 1.0f / (1.0f + __expf(-s)); break;
            default: y = fmaxf(s, 0.0f) + log1pf(__expf(-fabsf(s))); break; // softplus
        }
        mny = fminf(mny, y);  mxy = fmaxf(mxy, y);
    }
    #pragma unroll
    for (int off = 32; off > 0; off >>= 1) {
        mns = fminf(mns, __shfl_down(mns, off, 64));
        mxs = fmaxf(mxs, __shfl_down(mxs, off, 64));
        mny = fminf(mny, __shfl_down(mny, off, 64));
        mxy = fmaxf(mxy, __shfl_down(mxy, off, 64));
    }
    const int wave = tid >> 6, lane = tid & 63;
    if (lane == 0) { red[0][wave]=mns; red[1][wave]=mxs; red[2][wave]=mny; red[3][wave]=mxy; }
    __syncthreads();
    if (tid == 0) {
        float a=red[0][0], c=red[1][0], d=red[2][0], f=red[3][0];
        #pragma unroll
        for (int w=1; w<4; ++w) {
            a=fminf(a,red[0][w]); c=fmaxf(c,red[1][w]);
            d=fminf(d,red[2][w]); f=fmaxf(f,red[3][w]);
        }
        sst[0]=a; sst[1]=c; sst[2]=d; sst[3]=f;
    }
    __syncthreads();
    mns=sst[0]; mxs=sst[1]; mny=sst[2]; mxy=sst[3];

    const int r = chunk * 256 + tid;
    const float rr = (float)r * (1.0f / 1023.0f);
    float t0 = mns + (mxs - mns) * rr;  if (t0 == 0.0f) t0 = 1e-7f;
    float t1 = mny + (mxy - mny) * rr;  if (t1 == 0.0f) t1 = 1e-7f;

    const float yc01 = fminf(fmaxf(t1, KDE_EPS), 1.0f - KDE_EPS);
    const float ycp  = fmaxf(t1, KDE_EPS);
    float xi, ld;
    switch (selb) {
        case 0:  xi = 0.5f * t1;           ld = -0.6931471805599453f; break;
        case 1:  xi = t1 + 3.0f;           ld = 0.0f;                 break;
        case 2:  xi = 1.0f / t1;           ld = -2.0f * logf(fabsf(t1)); break;
        case 3:  xi = (t1 - 5.0f) * 1.25f; ld = 0.22314355131420976f; break;
        case 4:  xi = logf(yc01) - log1pf(-yc01);
                 ld = -logf(yc01) - log1pf(-yc01);                    break;
        default: { const float em = expm1f(ycp); xi = logf(em); ld = ycp - xi; } break;
    }

    const float tK  = t0 * SCALE;
    const float xiK = xi * SCALE;

    float acc0 = 0.0f, acc1 = 0.0f;
    const v4f* xs4 = (const v4f*)xsS;
    #pragma unroll 4
    for (int j4 = 0; j4 < NX / 4; ++j4) {
        const v4f xv = xs4[j4];              // ds_read_b128, broadcast
        float w;
        w = tK  - xv.x; acc0 += __builtin_amdgcn_exp2f(-(w * w));
        w = tK  - xv.y; acc0 += __builtin_amdgcn_exp2f(-(w * w));
        w = tK  - xv.z; acc0 += __builtin_amdgcn_exp2f(-(w * w));
        w = tK  - xv.w; acc0 += __builtin_amdgcn_exp2f(-(w * w));
        w = xiK - xv.x; acc1 += __builtin_amdgcn_exp2f(-(w * w));
        w = xiK - xv.y; acc1 += __builtin_amdgcn_exp2f(-(w * w));
        w = xiK - xv.z; acc1 += __builtin_amdgcn_exp2f(-(w * w));
        w = xiK - xv.w; acc1 += __builtin_amdgcn_exp2f(-(w * w));
    }

    const int slot_idx = *slotp;
    const size_t o = (size_t)b * NR + r;
    // log-space recombine: acc1==0 with large ld stays 0 (matches reference)
    if (slot_idx != 0) out[o] = acc0 * NORM;
    if (slot_idx != 1) out[(size_t)NB * NR + o] = __expf(__logf(acc1) + ld - LOGC);
}

extern "C" void kernel_launch(void* const* d_in, const int* in_sizes, int n_in,
                              void* d_out, int out_size, void* d_ws, size_t ws_size,
                              hipStream_t stream) {
    const float* inputs   = (const float*)d_in[0]; // (256,512)
    const float* bank     = (const float*)d_in[1]; // (128,512,1024)
    const float* noise    = (const float*)d_in[2]; // (512,2048)
    const int*   comp_idx = (const int*)d_in[3];   // (512,2048)
    const int*   sel      = (const int*)d_in[4];   // (512,)
    const int*   slotp    = (const int*)d_in[5];   // scalar
    float* out = (float*)d_out;

    kde_fused<<<GRID_TOTAL, 256, 0, stream>>>(
        inputs, (const v4f*)bank, noise, comp_idx, sel, slotp, out);
}